// Round 8
// baseline (178.372 us; speedup 1.0000x reference)
//
#include <hip/hip_runtime.h>

#define B_ 64
#define N_ 64
#define D_ 256
#define LAP_ 16
#define M_ 2016           // 64*63/2
#define TOK_ 2081         // 1 + 64 + 2016

typedef float v4f __attribute__((ext_vector_type(4)));

// Map linear upper-tri index m -> (i, j), i<j, row-major over triu(k=1).
__device__ __forceinline__ void ij_from_m(int m, int& i, int& j) {
    float fm = (float)m;
    int gi = (int)((127.0f - sqrtf(127.0f * 127.0f - 8.0f * fm)) * 0.5f);
    if (gi < 0) gi = 0;
    if (gi > 62) gi = 62;
    while (gi > 0 && (127 * gi - gi * gi) / 2 > m) gi--;
    while (gi < 62 && (127 * (gi + 1) - (gi + 1) * (gi + 1)) / 2 <= m) gi++;
    i = gi;
    j = gi + 1 + (m - (127 * gi - gi * gi) / 2);
}

// ---------------------------------------------------------------------------
// Kernel A: per-batch partials + everything small.
// Grid (B, 4), 256 threads, 4.3 KB LDS.
//   ws: base[256] | U[B][N][D] | V[B][N][D] | src[B][M] (ints)
// R8 change vs R7: ALL stores are plain (cached) stores — no nontemporal.
// Theory: nt bypasses L2 write-combining; cached full-line writes drain at
// the fill's demonstrated ~6.4 TB/s instead of ~2.4.
// ---------------------------------------------------------------------------
__global__ __launch_bounds__(256, 4) void prep_kernel(
    const int*   __restrict__ adj,
    const float* __restrict__ node_feats,
    const float* __restrict__ eigvec,
    const float* __restrict__ W_lap,
    const float* __restrict__ W_edge,
    const float* __restrict__ b_edge,
    const float* __restrict__ type_embed,
    const float* __restrict__ graph_tok,
    float*       __restrict__ out,
    float*       __restrict__ wsf,
    int*         __restrict__ src)
{
    __shared__ float sEig[N_ * LAP_];          // 4 KB
    __shared__ unsigned long long sWords[32];  // 2016-bit valid mask
    __shared__ int sPref[32];
    __shared__ int sTotal;

    const int b    = blockIdx.x;
    const int cg   = blockIdx.y;
    const int t    = threadIdx.x;
    const int wave = t >> 6, lane = t & 63;

    ((float4*)sEig)[t] = ((const float4*)(eigvec + (size_t)b * N_ * LAP_))[t];

    // ---- full valid bitmask via ballot ----
#pragma unroll
    for (int k = 0; k < 8; k++) {
        int m = k * 256 + t;
        int valid = 0;
        if (m < M_) {
            int i, j;
            ij_from_m(m, i, j);
            valid = (adj[b * (N_ * N_) + i * N_ + j] > 0) ? 1 : 0;
        }
        unsigned long long blt = __ballot(valid);
        if (lane == 0) sWords[k * 4 + wave] = blt;
    }

    // weights: U/V slice uses col = cg*64 + lane; node tokens use col = t
    const int colS = cg * 64 + lane;
    float w1c[LAP_], w2c[LAP_], wlc[LAP_];
#pragma unroll
    for (int l = 0; l < LAP_; l++) {
        w1c[l] = W_edge[(1 + l) * D_ + colS];
        w2c[l] = W_edge[(1 + LAP_ + l) * D_ + colS];
        wlc[l] = W_lap[l * D_ + t];
    }
    __syncthreads();   // sEig + sWords ready

    if (t < 32) {
        int cnt = __popcll(sWords[t]);
        int inc = cnt;
#pragma unroll
        for (int off = 1; off < 32; off <<= 1) {
            int v = __shfl_up(inc, off);
            if (lane >= off) inc += v;
        }
        sPref[t] = inc - cnt;
        if (t == 31) sTotal = inc;
    }
    __syncthreads();   // sPref/sTotal ready

    // ---- U,V column slice: wave handles 16 nodes, lane owns col colS ----
    float* Ub = wsf + 256 + (size_t)b * N_ * D_;
    float* Vb = Ub + (size_t)B_ * N_ * D_;
#pragma unroll 2
    for (int n16 = 0; n16 < 16; n16++) {
        int n = wave * 16 + n16;
        const float* e = sEig + n * LAP_;   // wave-uniform broadcast reads
        float aU = 0.0f, aV = 0.0f;
#pragma unroll
        for (int l = 0; l < LAP_; l++) {
            float el = e[l];
            aU += el * w1c[l];
            aV += el * w2c[l];
        }
        Ub[n * D_ + colS] = aU;
        Vb[n * D_ + colS] = aV;
    }

    // ---- node tokens: nodes [cg*16, cg*16+16), col = t ----
    float* outB = out + (size_t)b * TOK_ * D_;
#pragma unroll 4
    for (int k = 0; k < 16; k++) {
        int n = cg * 16 + k;
        float a = node_feats[((size_t)b * N_ + n) * D_ + t];
        const float* e = sEig + n * LAP_;
#pragma unroll
        for (int l = 0; l < LAP_; l++) a += e[l] * wlc[l];
        outB[(size_t)(1 + n) * D_ + t] = a;
    }

    // ---- inverse permutation src[p] = (i,j,valid) + pad mask ----
    const int total = sTotal;
    float* maskb = out + (size_t)B_ * TOK_ * D_ + (size_t)b * TOK_;
    for (int idx = t; idx < 504; idx += 256) {
        int m = cg * 504 + idx;
        int w = m >> 6, r = m & 63;
        unsigned long long word = sWords[w];
        int rank = sPref[w] + __popcll(word & ((1ull << r) - 1ull));
        int valid = (int)((word >> r) & 1ull);
        int p = valid ? rank : total + (m - rank);
        int i, j;
        ij_from_m(m, i, j);
        src[b * M_ + p] = i | (j << 6) | (valid << 12);
        maskb[1 + N_ + p] = valid ? 0.0f : 1.0f;
    }

    if (cg == 0) {
        wsf[t] = W_edge[t] + b_edge[t] + type_embed[D_ + t];  // base row
        outB[t] = graph_tok[t];                               // graph token
        if (t < 1 + N_) maskb[t] = 0.0f;                      // mask head
    }
}

// ---------------------------------------------------------------------------
// Kernel B: destination-ordered edge-token streamer. Grid 2048, 256 threads,
// zero LDS, 8 blocks/CU -> 32 waves/CU. Block owns a CONTIGUOUS 63-row
// destination range. Plain cached stores (R8: no nt).
// U/V gathers are random but L2-resident (128 KB/batch, batch pinned to
// XCD b&7).
// ---------------------------------------------------------------------------
__global__ __launch_bounds__(256, 8) void edge_kernel(
    const float* __restrict__ wsf,
    const int*   __restrict__ src,
    float*       __restrict__ out)
{
    const int bid  = blockIdx.x;         // 0..2047
    const int xcd  = bid & 7;
    const int idx  = bid >> 3;           // 0..255
    const int b    = ((idx & 7) << 3) | xcd;   // batch, pinned to XCD b&7
    const int s    = idx >> 3;           // 0..31: dest chunk within batch
    const int wave = threadIdx.x >> 6, lane = threadIdx.x & 63;

    v4f base4 = ((const v4f*)wsf)[lane];
    const float* Ub = wsf + 256 + (size_t)b * N_ * D_;
    const float* Vb = Ub + (size_t)B_ * N_ * D_;
    const int* sb = src + b * M_;
    float* outE = out + (size_t)b * TOK_ * D_ + (size_t)(1 + N_) * D_;

    const int p0 = s * 63;               // this block: dest rows [p0, p0+63)
    for (int p = p0 + wave; p < p0 + 63; p += 4) {
        int info = sb[p];                // wave-uniform broadcast load
        v4f val = {0.0f, 0.0f, 0.0f, 0.0f};
        if (info & (1 << 12)) {          // wave-uniform branch
            int si = info & 63, di = (info >> 6) & 63;
            v4f u = ((const v4f*)(Ub + si * D_))[lane];
            v4f v = ((const v4f*)(Vb + di * D_))[lane];
            val = base4 + u + v;
        }
        ((v4f*)(outE + (size_t)p * D_))[lane] = val;
    }
}

extern "C" void kernel_launch(void* const* d_in, const int* in_sizes, int n_in,
                              void* d_out, int out_size, void* d_ws, size_t ws_size,
                              hipStream_t stream) {
    const int*   adj        = (const int*)d_in[0];
    const float* node_feats = (const float*)d_in[1];
    const float* eigvec     = (const float*)d_in[2];
    const float* W_lap      = (const float*)d_in[3];
    const float* W_edge     = (const float*)d_in[4];
    const float* b_edge     = (const float*)d_in[5];
    const float* type_embed = (const float*)d_in[6];
    const float* graph_tok  = (const float*)d_in[7];
    float* out = (float*)d_out;

    // ws layout: base[256] | U[B][N][D] | V[B][N][D] | src[B][M] ints  (~8.8 MB)
    float* wsf = (float*)d_ws;
    int*   src = (int*)(wsf + 256 + 2 * (size_t)B_ * N_ * D_);

    prep_kernel<<<dim3(B_, 4), dim3(256), 0, stream>>>(
        adj, node_feats, eigvec, W_lap, W_edge, b_edge, type_embed, graph_tok,
        out, wsf, src);
    edge_kernel<<<dim3(2048), dim3(256), 0, stream>>>(wsf, src, out);
}

// Round 9
// 167.683 us; speedup vs baseline: 1.0637x; 1.0637x over previous
//
#include <hip/hip_runtime.h>

#define B_ 64
#define N_ 64
#define D_ 256
#define LAP_ 16
#define M_ 2016           // 64*63/2
#define TOK_ 2081         // 1 + 64 + 2016

typedef float v4f __attribute__((ext_vector_type(4)));

// Map linear upper-tri index m -> (i, j), i<j, row-major over triu(k=1).
__device__ __forceinline__ void ij_from_m(int m, int& i, int& j) {
    float fm = (float)m;
    int gi = (int)((127.0f - sqrtf(127.0f * 127.0f - 8.0f * fm)) * 0.5f);
    if (gi < 0) gi = 0;
    if (gi > 62) gi = 62;
    while (gi > 0 && (127 * gi - gi * gi) / 2 > m) gi--;
    while (gi < 62 && (127 * (gi + 1) - (gi + 1) * (gi + 1)) / 2 <= m) gi++;
    i = gi;
    j = gi + 1 + (m - (127 * gi - gi * gi) / 2);
}

// ---------------------------------------------------------------------------
// Kernel A: per-batch partials. Grid (B, 8) = 512 blocks (2/CU), 256 thr.
// R9 changes vs R8:
//  - adj staged into LDS via 4 coalesced int4 rounds; ballot reads LDS
//    (was: 8 serial rounds of scattered cold-HBM loads at 4 waves/CU).
//  - 8 blocks/batch (was 4): U-slice blocks (cg<4) and V-slice blocks
//    (cg>=4) are now separate -> double TLP, half the work per block.
//   ws: base[256] | U[B][N][D] | V[B][N][D] | src[B][M] (ints)
// ---------------------------------------------------------------------------
__global__ __launch_bounds__(256, 2) void prep_kernel(
    const int*   __restrict__ adj,
    const float* __restrict__ node_feats,
    const float* __restrict__ eigvec,
    const float* __restrict__ W_lap,
    const float* __restrict__ W_edge,
    const float* __restrict__ b_edge,
    const float* __restrict__ type_embed,
    const float* __restrict__ graph_tok,
    float*       __restrict__ out,
    float*       __restrict__ wsf,
    int*         __restrict__ src)
{
    __shared__ int   sAdj[N_ * N_];            // 16 KB
    __shared__ float sEig[N_ * LAP_];          // 4 KB
    __shared__ unsigned long long sWords[32];  // 2016-bit valid mask
    __shared__ int sPref[32];
    __shared__ int sTotal;

    const int b    = blockIdx.x;
    const int cg   = blockIdx.y;               // 0..7
    const int t    = threadIdx.x;
    const int wave = t >> 6, lane = t & 63;

    // ---- stage adj (coalesced int4) + eigvec into LDS ----
#pragma unroll
    for (int r = 0; r < 4; r++)
        ((int4*)sAdj)[r * 256 + t] =
            ((const int4*)(adj + (size_t)b * (N_ * N_)))[r * 256 + t];
    ((float4*)sEig)[t] = ((const float4*)(eigvec + (size_t)b * N_ * LAP_))[t];

    // weight loads (independent of the barrier; hide under staging)
    // U/V slice: cg<4 -> U cols (cg&3)*64+lane from W1; cg>=4 -> V from W2.
    const float* Wsel = (cg < 4) ? (W_edge + D_) : (W_edge + (1 + LAP_) * D_);
    const int colS = (cg & 3) * 64 + lane;
    float wc[LAP_], wlc[LAP_];
#pragma unroll
    for (int l = 0; l < LAP_; l++) {
        wc[l]  = Wsel[l * D_ + colS];
        wlc[l] = W_lap[l * D_ + t];
    }
    __syncthreads();   // sAdj + sEig ready

    // ---- ballot from LDS (latency ~LDS, fully pipelined) ----
#pragma unroll
    for (int k = 0; k < 8; k++) {
        int m = k * 256 + t;
        int valid = 0;
        if (m < M_) {
            int i, j;
            ij_from_m(m, i, j);
            valid = (sAdj[i * N_ + j] > 0) ? 1 : 0;
        }
        unsigned long long blt = __ballot(valid);
        if (lane == 0) sWords[k * 4 + wave] = blt;
    }
    __syncthreads();

    if (t < 32) {
        int cnt = __popcll(sWords[t]);
        int inc = cnt;
#pragma unroll
        for (int off = 1; off < 32; off <<= 1) {
            int v = __shfl_up(inc, off);
            if (lane >= off) inc += v;
        }
        sPref[t] = inc - cnt;
        if (t == 31) sTotal = inc;
    }
    __syncthreads();   // sPref/sTotal ready

    // ---- U-or-V column slice: wave handles 16 nodes, lane owns col colS ----
    float* Ub = wsf + 256 + (size_t)b * N_ * D_;
    float* Vb = Ub + (size_t)B_ * N_ * D_;
    float* Tb = (cg < 4) ? Ub : Vb;
#pragma unroll 2
    for (int n16 = 0; n16 < 16; n16++) {
        int n = wave * 16 + n16;
        const float* e = sEig + n * LAP_;   // wave-uniform broadcast reads
        float acc = 0.0f;
#pragma unroll
        for (int l = 0; l < LAP_; l++) acc += e[l] * wc[l];
        Tb[n * D_ + colS] = acc;
    }

    // ---- node tokens: nodes [cg*8, cg*8+8), col = t ----
    float* outB = out + (size_t)b * TOK_ * D_;
#pragma unroll 4
    for (int k = 0; k < 8; k++) {
        int n = cg * 8 + k;
        float a = node_feats[((size_t)b * N_ + n) * D_ + t];
        const float* e = sEig + n * LAP_;
#pragma unroll
        for (int l = 0; l < LAP_; l++) a += e[l] * wlc[l];
        outB[(size_t)(1 + n) * D_ + t] = a;
    }

    // ---- inverse permutation src[p] = (i,j,valid) + pad mask ----
    const int total = sTotal;
    float* maskb = out + (size_t)B_ * TOK_ * D_ + (size_t)b * TOK_;
    {
        int idx = t;                        // 252 edges/block: threads 0..251
        if (idx < 252) {
            int m = cg * 252 + idx;
            int w = m >> 6, r = m & 63;
            unsigned long long word = sWords[w];
            int rank = sPref[w] + __popcll(word & ((1ull << r) - 1ull));
            int valid = (int)((word >> r) & 1ull);
            int p = valid ? rank : total + (m - rank);
            int i, j;
            ij_from_m(m, i, j);
            src[b * M_ + p] = i | (j << 6) | (valid << 12);
            maskb[1 + N_ + p] = valid ? 0.0f : 1.0f;
        }
    }

    if (cg == 0) {
        wsf[t] = W_edge[t] + b_edge[t] + type_embed[D_ + t];  // base row
        outB[t] = graph_tok[t];                               // graph token
        if (t < 1 + N_) maskb[t] = 0.0f;                      // mask head
    }
}

// ---------------------------------------------------------------------------
// Kernel B: destination-ordered edge-token streamer. Grid 2048, 256 threads,
// zero LDS, 8 blocks/CU -> 32 waves/CU.
// R9 change: the per-iteration dependent scalar src load is gone — each wave
// prefetches its 16 info words with ONE vector load (lanes 0..15) and
// broadcasts per iteration via __shfl (VALU). Chain is now shfl -> gather ->
// store, and the fixed 16-trip loop unrolls 4x (4 gathers in flight).
// ---------------------------------------------------------------------------
__global__ __launch_bounds__(256, 8) void edge_kernel(
    const float* __restrict__ wsf,
    const int*   __restrict__ src,
    float*       __restrict__ out)
{
    const int bid  = blockIdx.x;         // 0..2047
    const int xcd  = bid & 7;
    const int idx  = bid >> 3;           // 0..255
    const int b    = ((idx & 7) << 3) | xcd;   // batch, pinned to XCD b&7
    const int s    = idx >> 3;           // 0..31: dest chunk within batch
    const int wave = threadIdx.x >> 6, lane = threadIdx.x & 63;

    v4f base4 = ((const v4f*)wsf)[lane];
    const float* Ub = wsf + 256 + (size_t)b * N_ * D_;
    const float* Vb = Ub + (size_t)B_ * N_ * D_;
    const int* sb = src + b * M_;
    float* outE = out + (size_t)b * TOK_ * D_ + (size_t)(1 + N_) * D_;

    const int p0 = s * 63;               // this block: dest rows [p0, p0+63)
    // wave handles p = p0 + wave + 4q; prefetch all its infos in one load
    const int q15 = lane & 15;
    const int nq  = (63 - wave + 3) >> 2;          // 16,16,16,15
    int myinfo = (wave + 4 * q15 < 63) ? sb[p0 + wave + 4 * q15] : 0;

#pragma unroll 4
    for (int q = 0; q < nq; q++) {
        int info = __shfl(myinfo, q);    // VALU broadcast, no memory chain
        int p = p0 + wave + 4 * q;
        v4f val = {0.0f, 0.0f, 0.0f, 0.0f};
        if (info & (1 << 12)) {          // wave-uniform branch
            int si = info & 63, di = (info >> 6) & 63;
            v4f u = ((const v4f*)(Ub + si * D_))[lane];
            v4f v = ((const v4f*)(Vb + di * D_))[lane];
            val = base4 + u + v;
        }
        ((v4f*)(outE + (size_t)p * D_))[lane] = val;
    }
}

extern "C" void kernel_launch(void* const* d_in, const int* in_sizes, int n_in,
                              void* d_out, int out_size, void* d_ws, size_t ws_size,
                              hipStream_t stream) {
    const int*   adj        = (const int*)d_in[0];
    const float* node_feats = (const float*)d_in[1];
    const float* eigvec     = (const float*)d_in[2];
    const float* W_lap      = (const float*)d_in[3];
    const float* W_edge     = (const float*)d_in[4];
    const float* b_edge     = (const float*)d_in[5];
    const float* type_embed = (const float*)d_in[6];
    const float* graph_tok  = (const float*)d_in[7];
    float* out = (float*)d_out;

    // ws layout: base[256] | U[B][N][D] | V[B][N][D] | src[B][M] ints  (~8.8 MB)
    float* wsf = (float*)d_ws;
    int*   src = (int*)(wsf + 256 + 2 * (size_t)B_ * N_ * D_);

    prep_kernel<<<dim3(B_, 8), dim3(256), 0, stream>>>(
        adj, node_feats, eigvec, W_lap, W_edge, b_edge, type_embed, graph_tok,
        out, wsf, src);
    edge_kernel<<<dim3(2048), dim3(256), 0, stream>>>(wsf, src, out);
}